// Round 1
// baseline (450.146 us; speedup 1.0000x reference)
//
#include <hip/hip_runtime.h>
#include <math.h>

// Fused dual-LeNet + len-19 full convolution + log.
// 2 samples (4 LeNet instances) per block, 256 threads.
// Round-11: conv2 moves to MFMA (v_mfma_f32_16x16x32_f16).
//  * A = W2 staged as [o][kp] half2 rows (kp=(icp,ky,kx), padded 75->84,
//    zeros at kp>=75); each wave preloads 5 k-step A-fragments (b128).
//  * B = im2col of s_p1h, never materialized: per MFMA the lane's 8-half
//    fragment = 4 ds_read_b32 half2 gathers at koff(kp)+colshift(n),
//    kp clamped to 74 (garbage B only meets zero A).
//  * one wave per instance, 4 N-tiles x 5 k-steps = 20 mfma/wave replaces
//    1200 v_dot2 + 54 ds_read_b128 + 75 ds_read_b32 per wave.
//  * pool2x2 via C/D layout (col=lane&15,row=(lane>>4)*4+reg):
//    shfl_xor(1) = x-pair, shfl_xor(8) = y-pair, then bias+relu+store.
// Everything else = R10 (best so far: 353 us counter): f16 channel-pair
// p1 layout, LDS-resident weights, padded strides, merged tail.

#define SPB 2            // samples per block
#define P1H_IN 440       // s_p1h instance stride in half2 (mod 32 = 24)
#define P1H_IC 144       // channel-pair stride in half2 (3 pairs per inst)

typedef _Float16 f16x2 __attribute__((ext_vector_type(2)));
typedef _Float16 half8 __attribute__((ext_vector_type(8)));
typedef float floatx4 __attribute__((ext_vector_type(4)));

__global__ __launch_bounds__(256) void lenet_fused(
    const float* __restrict__ x,     // [B,2,28,28]
    const float* __restrict__ cw1,   // [6,1,5,5]
    const float* __restrict__ cb1,   // [6]
    const float* __restrict__ cw2,   // [16,6,5,5]
    const float* __restrict__ cb2,   // [16]
    const float* __restrict__ fw1,   // [120,256]
    const float* __restrict__ fb1,   // [120]
    const float* __restrict__ fw2,   // [84,120]
    const float* __restrict__ fb2,   // [84]
    const float* __restrict__ fw3,   // [10,84]
    const float* __restrict__ fb3,   // [10]
    float* __restrict__ out)         // [B,19]
{
    const int tid = threadIdx.x;
    const int b0  = blockIdx.x * SPB;

    __shared__ __align__(16) float s_pool[4 * 784];      // 12544 B (imgs; reused)
    __shared__ __align__(16) f16x2 s_p1h [4 * P1H_IN];   //  7040 B
    __shared__ __align__(16) float s_w1t [25 * 8];       //   800 B  [k][o]
    __shared__ float s_b1[8];
    __shared__ __align__(16) f16x2 s_w2A [16 * 84];      //  5376 B  A-layout [o][kp]
    __shared__ float s_b2[16];
    // total ~25.9 KB -> 6 blocks/CU

    float* s_img = s_pool;           // 3136 floats (4 inst x 784)
    float* s_p2  = s_pool;           // 1024
    float* s_f1  = s_pool + 1024;    // 480
    float* s_f2  = s_pool + 1504;    // 336
    float* s_log = s_pool + 1840;    // 40

    // ---- stage images + weights ----
    {
        const float4* xb = (const float4*)(x + (size_t)b0 * 1568);
        float4* si = (float4*)s_img;
        for (int i = tid; i < 784; i += 256) si[i] = xb[i];
    }
    for (int i = tid; i < 150; i += 256) {       // cw1 -> [k][o], stride 8
        int o = i / 25, k = i % 25;
        s_w1t[k * 8 + o] = cw1[i];
    }
    for (int i = tid; i < 16 * 84; i += 256) {   // cw2 -> MFMA A rows [o][kp]
        int o = i / 84, kp = i % 84;
        f16x2 w2;
        if (kp < 75) {
            int icp = kp / 25, r = kp % 25;      // kp = icp*25 + ky*5 + kx
            float we = cw2[o * 150 + (2 * icp    ) * 25 + r];
            float wo = cw2[o * 150 + (2 * icp + 1) * 25 + r];
            w2.x = (_Float16)we; w2.y = (_Float16)wo;
        } else {
            w2.x = (_Float16)0.f; w2.y = (_Float16)0.f;  // zero-pad k 150..159
        }
        s_w2A[i] = w2;
    }
    if (tid < 6)  s_b1[tid] = cb1[tid];
    if (tid < 16) s_b2[tid] = cb2[tid];
    __syncthreads();

#define LOAD_ROW12(dst, ptr)                                                   \
    {   const float4* _rp = (const float4*)(ptr);                              \
        float4 _q0 = _rp[0], _q1 = _rp[1], _q2 = _rp[2];                       \
        dst[0]=_q0.x; dst[1]=_q0.y; dst[2]=_q0.z; dst[3]=_q0.w;                \
        dst[4]=_q1.x; dst[5]=_q1.y; dst[6]=_q1.z; dst[7]=_q1.w;                \
        dst[8]=_q2.x; dst[9]=_q2.y; dst[10]=_q2.z; dst[11]=_q2.w; }

#define FMA8(accv, rowv, wv)                                                   \
    _Pragma("unroll")                                                          \
    for (int kx = 0; kx < 5; ++kx) {                                           \
        float _w = (wv)[kx];                                                   \
        _Pragma("unroll")                                                      \
        for (int cc = 0; cc < 8; ++cc)                                         \
            accv[cc] = fmaf((rowv)[cc + kx], _w, accv[cc]);                    \
    }

    // ---- conv1 5x5 (1->6) + pool2x2 + relu : 864 tasks, o fastest ----
#pragma unroll 1
    for (int t = tid; t < 864; t += 256) {
        int o  = t % 6;  int u = t / 6;
        int g  = u % 3;  int v = u / 3;
        int py = v % 12; int inst = v / 12;

        const float* wt   = &s_w1t[o];           // w[k] at wt[k*8]
        const float* base = &s_img[inst * 784 + (py * 2) * 28 + g * 8];

        float acc0[8], acc1[8];
#pragma unroll
        for (int i = 0; i < 8; ++i) { acc0[i] = 0.f; acc1[i] = 0.f; }

        float row[12], wa[5], wb[5];
        LOAD_ROW12(row, base);
#pragma unroll
        for (int kx = 0; kx < 5; ++kx) wa[kx] = wt[kx * 8];
        FMA8(acc0, row, wa);
        LOAD_ROW12(row, base + 28);
#pragma unroll
        for (int kx = 0; kx < 5; ++kx) wb[kx] = wt[(5 + kx) * 8];
        FMA8(acc0, row, wb); FMA8(acc1, row, wa);
        LOAD_ROW12(row, base + 56);
#pragma unroll
        for (int kx = 0; kx < 5; ++kx) wa[kx] = wt[(10 + kx) * 8];
        FMA8(acc0, row, wa); FMA8(acc1, row, wb);
        LOAD_ROW12(row, base + 84);
#pragma unroll
        for (int kx = 0; kx < 5; ++kx) wb[kx] = wt[(15 + kx) * 8];
        FMA8(acc0, row, wb); FMA8(acc1, row, wa);
        LOAD_ROW12(row, base + 112);
#pragma unroll
        for (int kx = 0; kx < 5; ++kx) wa[kx] = wt[(20 + kx) * 8];
        FMA8(acc0, row, wa); FMA8(acc1, row, wb);
        LOAD_ROW12(row, base + 140);
        FMA8(acc1, row, wa);

        float bia = s_b1[o];
        float m0 = fmaxf(fmaxf(fmaxf(acc0[0], acc0[1]), fmaxf(acc1[0], acc1[1])) + bia, 0.f);
        float m1 = fmaxf(fmaxf(fmaxf(acc0[2], acc0[3]), fmaxf(acc1[2], acc1[3])) + bia, 0.f);
        float m2 = fmaxf(fmaxf(fmaxf(acc0[4], acc0[5]), fmaxf(acc1[4], acc1[5])) + bia, 0.f);
        float m3 = fmaxf(fmaxf(fmaxf(acc0[6], acc0[7]), fmaxf(acc1[6], acc1[7])) + bia, 0.f);

        // store as f16 into channel-pair layout: half2[inst][o>>1][py][px], lane o&1
        _Float16* dst = (_Float16*)&s_p1h[inst * P1H_IN + (o >> 1) * P1H_IC + py * 12 + g * 4];
        dst += (o & 1);
        dst[0] = (_Float16)m0; dst[2] = (_Float16)m1;
        dst[4] = (_Float16)m2; dst[6] = (_Float16)m3;
    }
    __syncthreads();

    // ---- conv2 5x5 (6->16) + pool2x2 + relu : MFMA 16x16x32 f16 ----
    // D[16 x 256] = W[16 x 160] * im2col[160 x 256]; one wave per instance.
    // k (half) = 2*kp + c; kp = icp*25 + ky*5 + kx; c = channel parity.
    {
        const int lane = tid & 63;
        const int wv   = tid >> 6;               // instance
        const int g    = lane >> 4;              // k-group
        const int cn   = lane & 15;              // A row (=o) / B col (=n%16)

        // A fragments: halfs wA[cn][ks*32 + g*8 + 0..7], row stride 168 halfs
        half8 afr[5];
        const _Float16* wA = (const _Float16*)s_w2A;
#pragma unroll
        for (int ks = 0; ks < 5; ++ks)
            afr[ks] = *(const half8*)(wA + cn * 168 + ks * 32 + g * 8);

        float bias4[4];
#pragma unroll
        for (int r = 0; r < 4; ++r) bias4[r] = s_b2[g * 4 + r];

        // column n = ntl*16 + cn -> (y,x) = (n>>3, n&7); shift in half2 units
        const int csb = (cn >> 3) * 12 + (cn & 7);           // + 24*ntl per tile
        const f16x2* pbase = s_p1h + wv * P1H_IN + csb;

        floatx4 zero4 = {0.f, 0.f, 0.f, 0.f};
        floatx4 acc[4] = {zero4, zero4, zero4, zero4};

#pragma unroll
        for (int ks = 0; ks < 5; ++ks) {
            int ko[4];
#pragma unroll
            for (int j = 0; j < 4; ++j) {
                int kp = ks * 16 + g * 4 + j;
                kp = kp > 74 ? 74 : kp;          // clamp: garbage meets zero A
                int icp = (int)((unsigned)kp / 25u);
                int r   = kp - icp * 25;
                int ky  = (int)((unsigned)r / 5u);
                int kx  = r - ky * 5;
                ko[j] = icp * P1H_IC + ky * 12 + kx;
            }
#pragma unroll
            for (int ntl = 0; ntl < 4; ++ntl) {
                union { half8 h8; f16x2 h2[4]; } bp;
                bp.h2[0] = pbase[ko[0] + 24 * ntl];
                bp.h2[1] = pbase[ko[1] + 24 * ntl];
                bp.h2[2] = pbase[ko[2] + 24 * ntl];
                bp.h2[3] = pbase[ko[3] + 24 * ntl];
                acc[ntl] = __builtin_amdgcn_mfma_f32_16x16x32_f16(
                    afr[ks], bp.h8, acc[ntl], 0, 0, 0);
            }
        }

        // pool 2x2 + bias + relu + store. D value at (lane, reg r, tile ntl):
        // row o = g*4+r, col n = ntl*16+cn -> y in {2ntl,2ntl+1}, x = cn&7.
        // x-pair = lane^1, y-pair = lane^8; lanes with (lane&9)==0 write.
        const int px = (lane & 7) >> 1;
        const bool wr = (lane & 9) == 0;
        float* p2o = s_p2 + wv * 256 + px;       // + o*16 + ntl*4
#pragma unroll
        for (int ntl = 0; ntl < 4; ++ntl) {
#pragma unroll
            for (int r = 0; r < 4; ++r) {
                float v = acc[ntl][r];
                v = fmaxf(v, __shfl_xor(v, 1));
                v = fmaxf(v, __shfl_xor(v, 8));
                v = fmaxf(v + bias4[r], 0.f);
                if (wr) p2o[(g * 4 + r) * 16 + ntl * 4] = v;
            }
        }
    }
    __syncthreads();

    // ---- fc1: 256 -> 120, relu. 240 lanes, 2 instances each ----
    if (tid < 240) {
        int o  = tid % 120;
        int pr = tid / 120;
        const float4* wr = (const float4*)(fw1 + o * 256);
        const float4* q0 = (const float4*)(s_p2 + (2 * pr    ) * 256);
        const float4* q1 = (const float4*)(s_p2 + (2 * pr + 1) * 256);
        float a0 = 0.f, a1 = 0.f;
#pragma unroll 4
        for (int k = 0; k < 64; ++k) {
            float4 w4 = wr[k];
            float4 p;
            p = q0[k]; a0 = fmaf(w4.x,p.x,a0); a0 = fmaf(w4.y,p.y,a0); a0 = fmaf(w4.z,p.z,a0); a0 = fmaf(w4.w,p.w,a0);
            p = q1[k]; a1 = fmaf(w4.x,p.x,a1); a1 = fmaf(w4.y,p.y,a1); a1 = fmaf(w4.z,p.z,a1); a1 = fmaf(w4.w,p.w,a1);
        }
        float bb = fb1[o];
        s_f1[(2 * pr    ) * 120 + o] = fmaxf(a0 + bb, 0.f);
        s_f1[(2 * pr + 1) * 120 + o] = fmaxf(a1 + bb, 0.f);
    }
    __syncthreads();

    // ---- fc2: 120 -> 84, relu. 168 lanes, 2 instances each ----
    if (tid < 168) {
        int o  = tid % 84;
        int pr = tid / 84;
        const float4* wr = (const float4*)(fw2 + o * 120);
        const float4* q0 = (const float4*)(s_f1 + (2 * pr    ) * 120);
        const float4* q1 = (const float4*)(s_f1 + (2 * pr + 1) * 120);
        float a0 = 0.f, a1 = 0.f;
#pragma unroll 5
        for (int k = 0; k < 30; ++k) {
            float4 w4 = wr[k];
            float4 p;
            p = q0[k]; a0 = fmaf(w4.x,p.x,a0); a0 = fmaf(w4.y,p.y,a0); a0 = fmaf(w4.z,p.z,a0); a0 = fmaf(w4.w,p.w,a0);
            p = q1[k]; a1 = fmaf(w4.x,p.x,a1); a1 = fmaf(w4.y,p.y,a1); a1 = fmaf(w4.z,p.z,a1); a1 = fmaf(w4.w,p.w,a1);
        }
        float bb = fb2[o];
        s_f2[(2 * pr    ) * 84 + o] = fmaxf(a0 + bb, 0.f);
        s_f2[(2 * pr + 1) * 84 + o] = fmaxf(a1 + bb, 0.f);
    }
    __syncthreads();

    // ---- fc3: 84 -> 10. 40 lanes ----
    if (tid < 40) {
        int o    = tid % 10;
        int inst = tid / 10;
        const float4* wr = (const float4*)(fw3 + o * 84);
        const float4* q0 = (const float4*)(s_f2 + inst * 84);
        float a0 = 0.f;
#pragma unroll
        for (int k = 0; k < 21; ++k) {
            float4 w4 = wr[k];
            float4 p = q0[k];
            a0 = fmaf(w4.x,p.x,a0); a0 = fmaf(w4.y,p.y,a0); a0 = fmaf(w4.z,p.z,a0); a0 = fmaf(w4.w,p.w,a0);
        }
        s_log[inst * 10 + o] = a0 + fb3[o];
    }
    __syncthreads();

    // ---- softmax (in-lane) + full convolution (len 19) + log ----
    if (tid < 19 * SPB) {
        int ls = tid / 19;
        int t  = tid % 19;
        const float* la = &s_log[(ls * 2 + 0) * 10];
        const float* lb = &s_log[(ls * 2 + 1) * 10];
        float pa[10], pb[10];
        float mxa = la[0], mxb = lb[0];
#pragma unroll
        for (int j = 1; j < 10; ++j) { mxa = fmaxf(mxa, la[j]); mxb = fmaxf(mxb, lb[j]); }
        float sa = 0.f, sb = 0.f;
#pragma unroll
        for (int j = 0; j < 10; ++j) {
            pa[j] = __expf(la[j] - mxa); sa += pa[j];
            pb[j] = __expf(lb[j] - mxb); sb += pb[j];
        }
        float inv = 1.f / (sa * sb);
        int jlo = t - 9 > 0 ? t - 9 : 0;
        int jhi = t < 9 ? t : 9;
        float z = 0.f;
        for (int j = jlo; j <= jhi; ++j)
            z += pa[j] * pb[t - j];
        out[(size_t)(b0 + ls) * 19 + t] = __logf(z * inv);
    }
}

extern "C" void kernel_launch(void* const* d_in, const int* in_sizes, int n_in,
                              void* d_out, int out_size, void* d_ws, size_t ws_size,
                              hipStream_t stream) {
    const float* x   = (const float*)d_in[0];
    const float* cw1 = (const float*)d_in[1];
    const float* cb1 = (const float*)d_in[2];
    const float* cw2 = (const float*)d_in[3];
    const float* cb2 = (const float*)d_in[4];
    const float* fw1 = (const float*)d_in[5];
    const float* fb1 = (const float*)d_in[6];
    const float* fw2 = (const float*)d_in[7];
    const float* fb2 = (const float*)d_in[8];
    const float* fw3 = (const float*)d_in[9];
    const float* fb3 = (const float*)d_in[10];
    float* out = (float*)d_out;

    const int B = in_sizes[0] / (2 * 28 * 28);   // 16384

    lenet_fused<<<B / SPB, 256, 0, stream>>>(x, cw1, cb1, cw2, cb2,
                                             fw1, fb1, fw2, fb2, fw3, fb3, out);
}

// Round 2
// 327.510 us; speedup vs baseline: 1.3745x; 1.3745x over previous
//
#include <hip/hip_runtime.h>
#include <math.h>

// Fused dual-LeNet + len-19 full convolution + log.
// Round-12: SPB 2 -> 4 (8 LeNet instances / block, 256 threads) to break the
// barrier-phase convoy (R11 showed stall-bound: VALU cut gave 0 speedup).
//  * every phase now carries 2x independent work per thread (ILP):
//    conv2 = 2 instances per wave, shared A-frags + gather offsets, two
//    independent MFMA chains; fc1/fc2 = 4 instance-dots per lane.
//  * fc1/fc2 lane-pairing (o=tid>>1, pr=tid&1): each weight row read once
//    per lane pair -> fw1 L2 traffic per sample 4x lower, fw2 2x.
//  * barriers per sample halved (6 per 4 samples).
//  * LDS 45.4 KB -> 3 blocks/CU (12 waves); trading lockstepped occupancy
//    for intra-wave ILP is the point of this round.
// Numerics identical to R11 (same f16 quantization points, same per-dot
// accumulation order): expect absmax == 0.03125 unchanged.

#define SPB 4            // samples per block (2 pairs, 8 instances)
#define P1H_IN 440       // s_p1h instance stride in half2
#define P1H_IC 144       // channel-pair stride in half2 (3 pairs per inst)

typedef _Float16 f16x2 __attribute__((ext_vector_type(2)));
typedef _Float16 half8 __attribute__((ext_vector_type(8)));
typedef float floatx4 __attribute__((ext_vector_type(4)));

__global__ __launch_bounds__(256, 3) void lenet_fused(
    const float* __restrict__ x,     // [B,2,28,28]
    const float* __restrict__ cw1,   // [6,1,5,5]
    const float* __restrict__ cb1,   // [6]
    const float* __restrict__ cw2,   // [16,6,5,5]
    const float* __restrict__ cb2,   // [16]
    const float* __restrict__ fw1,   // [120,256]
    const float* __restrict__ fb1,   // [120]
    const float* __restrict__ fw2,   // [84,120]
    const float* __restrict__ fb2,   // [84]
    const float* __restrict__ fw3,   // [10,84]
    const float* __restrict__ fb3,   // [10]
    float* __restrict__ out)         // [B,19]
{
    const int tid = threadIdx.x;
    const int b0  = blockIdx.x * SPB;

    __shared__ __align__(16) float s_pool[8 * 784];      // 25088 B (imgs; reused)
    __shared__ __align__(16) f16x2 s_p1h [8 * P1H_IN];   // 14080 B
    __shared__ __align__(16) float s_w1t [25 * 8];       //   800 B  [k][o]
    __shared__ float s_b1[8];
    __shared__ __align__(16) f16x2 s_w2A [16 * 84];      //  5376 B  A-layout [o][kp]
    __shared__ float s_b2[16];
    // total ~45.4 KB -> 3 blocks/CU

    float* s_img = s_pool;           // 6272 floats (8 inst x 784)
    float* s_p2  = s_pool;           // 2048
    float* s_f1  = s_pool + 2048;    // 960
    float* s_f2  = s_pool + 3008;    // 672
    float* s_log = s_pool + 3680;    // 80

    // ---- stage images + weights ----
    {
        const float4* xb = (const float4*)(x + (size_t)b0 * 1568);
        float4* si = (float4*)s_img;
        for (int i = tid; i < 1568; i += 256) si[i] = xb[i];
    }
    for (int i = tid; i < 150; i += 256) {       // cw1 -> [k][o], stride 8
        int o = i / 25, k = i % 25;
        s_w1t[k * 8 + o] = cw1[i];
    }
    for (int i = tid; i < 16 * 84; i += 256) {   // cw2 -> MFMA A rows [o][kp]
        int o = i / 84, kp = i % 84;
        f16x2 w2;
        if (kp < 75) {
            int icp = kp / 25, r = kp % 25;      // kp = icp*25 + ky*5 + kx
            float we = cw2[o * 150 + (2 * icp    ) * 25 + r];
            float wo = cw2[o * 150 + (2 * icp + 1) * 25 + r];
            w2.x = (_Float16)we; w2.y = (_Float16)wo;
        } else {
            w2.x = (_Float16)0.f; w2.y = (_Float16)0.f;  // zero-pad k 150..159
        }
        s_w2A[i] = w2;
    }
    if (tid < 6)  s_b1[tid] = cb1[tid];
    if (tid < 16) s_b2[tid] = cb2[tid];
    __syncthreads();

#define LOAD_ROW12(dst, ptr)                                                   \
    {   const float4* _rp = (const float4*)(ptr);                              \
        float4 _q0 = _rp[0], _q1 = _rp[1], _q2 = _rp[2];                       \
        dst[0]=_q0.x; dst[1]=_q0.y; dst[2]=_q0.z; dst[3]=_q0.w;                \
        dst[4]=_q1.x; dst[5]=_q1.y; dst[6]=_q1.z; dst[7]=_q1.w;                \
        dst[8]=_q2.x; dst[9]=_q2.y; dst[10]=_q2.z; dst[11]=_q2.w; }

#define FMA8(accv, rowv, wv)                                                   \
    _Pragma("unroll")                                                          \
    for (int kx = 0; kx < 5; ++kx) {                                           \
        float _w = (wv)[kx];                                                   \
        _Pragma("unroll")                                                      \
        for (int cc = 0; cc < 8; ++cc)                                         \
            accv[cc] = fmaf((rowv)[cc + kx], _w, accv[cc]);                    \
    }

    // ---- conv1 5x5 (1->6) + pool2x2 + relu : 1728 tasks, o fastest ----
#pragma unroll 1
    for (int t = tid; t < 1728; t += 256) {
        int o  = t % 6;  int u = t / 6;
        int g  = u % 3;  int v = u / 3;
        int py = v % 12; int inst = v / 12;      // 0..7

        const float* wt   = &s_w1t[o];           // w[k] at wt[k*8]
        const float* base = &s_img[inst * 784 + (py * 2) * 28 + g * 8];

        float acc0[8], acc1[8];
#pragma unroll
        for (int i = 0; i < 8; ++i) { acc0[i] = 0.f; acc1[i] = 0.f; }

        float row[12], wa[5], wb[5];
        LOAD_ROW12(row, base);
#pragma unroll
        for (int kx = 0; kx < 5; ++kx) wa[kx] = wt[kx * 8];
        FMA8(acc0, row, wa);
        LOAD_ROW12(row, base + 28);
#pragma unroll
        for (int kx = 0; kx < 5; ++kx) wb[kx] = wt[(5 + kx) * 8];
        FMA8(acc0, row, wb); FMA8(acc1, row, wa);
        LOAD_ROW12(row, base + 56);
#pragma unroll
        for (int kx = 0; kx < 5; ++kx) wa[kx] = wt[(10 + kx) * 8];
        FMA8(acc0, row, wa); FMA8(acc1, row, wb);
        LOAD_ROW12(row, base + 84);
#pragma unroll
        for (int kx = 0; kx < 5; ++kx) wb[kx] = wt[(15 + kx) * 8];
        FMA8(acc0, row, wb); FMA8(acc1, row, wa);
        LOAD_ROW12(row, base + 112);
#pragma unroll
        for (int kx = 0; kx < 5; ++kx) wa[kx] = wt[(20 + kx) * 8];
        FMA8(acc0, row, wa); FMA8(acc1, row, wb);
        LOAD_ROW12(row, base + 140);
        FMA8(acc1, row, wa);

        float bia = s_b1[o];
        float m0 = fmaxf(fmaxf(fmaxf(acc0[0], acc0[1]), fmaxf(acc1[0], acc1[1])) + bia, 0.f);
        float m1 = fmaxf(fmaxf(fmaxf(acc0[2], acc0[3]), fmaxf(acc1[2], acc1[3])) + bia, 0.f);
        float m2 = fmaxf(fmaxf(fmaxf(acc0[4], acc0[5]), fmaxf(acc1[4], acc1[5])) + bia, 0.f);
        float m3 = fmaxf(fmaxf(fmaxf(acc0[6], acc0[7]), fmaxf(acc1[6], acc1[7])) + bia, 0.f);

        // store as f16 into channel-pair layout: half2[inst][o>>1][py][px], lane o&1
        _Float16* dst = (_Float16*)&s_p1h[inst * P1H_IN + (o >> 1) * P1H_IC + py * 12 + g * 4];
        dst += (o & 1);
        dst[0] = (_Float16)m0; dst[2] = (_Float16)m1;
        dst[4] = (_Float16)m2; dst[6] = (_Float16)m3;
    }
    __syncthreads();

    // ---- conv2 5x5 (6->16) + pool2x2 + relu : MFMA 16x16x32 f16 ----
    // D[16 x 256] = W[16 x 160] * im2col[160 x 256]; one wave per 2 instances
    // (wv0 and wv0+4): shared A-frags + gather offsets, 2 independent chains.
    {
        const int lane = tid & 63;
        const int wv0  = tid >> 6;               // instance pair: wv0, wv0+4
        const int g    = lane >> 4;              // k-group
        const int cn   = lane & 15;              // A row (=o) / B col (=n%16)

        // A fragments: halfs wA[cn][ks*32 + g*8 + 0..7], row stride 168 halfs
        half8 afr[5];
        const _Float16* wA = (const _Float16*)s_w2A;
#pragma unroll
        for (int ks = 0; ks < 5; ++ks)
            afr[ks] = *(const half8*)(wA + cn * 168 + ks * 32 + g * 8);

        float bias4[4];
#pragma unroll
        for (int r = 0; r < 4; ++r) bias4[r] = s_b2[g * 4 + r];

        // column n = ntl*16 + cn -> (y,x) = (n>>3, n&7); shift in half2 units
        const int csb = (cn >> 3) * 12 + (cn & 7);           // + 24*ntl per tile
        const f16x2* pbA = s_p1h + wv0 * P1H_IN + csb;
        const f16x2* pbB = pbA + 4 * P1H_IN;

        floatx4 zero4 = {0.f, 0.f, 0.f, 0.f};
        floatx4 accA[4] = {zero4, zero4, zero4, zero4};
        floatx4 accB[4] = {zero4, zero4, zero4, zero4};

#pragma unroll
        for (int ks = 0; ks < 5; ++ks) {
            int ko[4];
#pragma unroll
            for (int j = 0; j < 4; ++j) {
                int kp = ks * 16 + g * 4 + j;
                kp = kp > 74 ? 74 : kp;          // clamp: garbage meets zero A
                int icp = (int)((unsigned)kp / 25u);
                int r   = kp - icp * 25;
                int ky  = (int)((unsigned)r / 5u);
                int kx  = r - ky * 5;
                ko[j] = icp * P1H_IC + ky * 12 + kx;
            }
#pragma unroll
            for (int ntl = 0; ntl < 4; ++ntl) {
                union { half8 h8; f16x2 h2[4]; } bpA, bpB;
                bpA.h2[0] = pbA[ko[0] + 24 * ntl];
                bpA.h2[1] = pbA[ko[1] + 24 * ntl];
                bpA.h2[2] = pbA[ko[2] + 24 * ntl];
                bpA.h2[3] = pbA[ko[3] + 24 * ntl];
                bpB.h2[0] = pbB[ko[0] + 24 * ntl];
                bpB.h2[1] = pbB[ko[1] + 24 * ntl];
                bpB.h2[2] = pbB[ko[2] + 24 * ntl];
                bpB.h2[3] = pbB[ko[3] + 24 * ntl];
                accA[ntl] = __builtin_amdgcn_mfma_f32_16x16x32_f16(
                    afr[ks], bpA.h8, accA[ntl], 0, 0, 0);
                accB[ntl] = __builtin_amdgcn_mfma_f32_16x16x32_f16(
                    afr[ks], bpB.h8, accB[ntl], 0, 0, 0);
            }
        }

        // pool 2x2 + bias + relu + store, for both instances.
        // D value at (lane, reg r, tile ntl): row o = g*4+r, col n = ntl*16+cn
        // -> y in {2ntl,2ntl+1}, x = cn&7. x-pair = lane^1, y-pair = lane^8.
        const int px = (lane & 7) >> 1;
        const bool wrp = (lane & 9) == 0;

#define CONV2_EPI(accv, instv)                                                 \
        {   float* p2o = s_p2 + (instv) * 256 + px;                            \
            _Pragma("unroll")                                                  \
            for (int ntl = 0; ntl < 4; ++ntl) {                                \
                _Pragma("unroll")                                              \
                for (int r = 0; r < 4; ++r) {                                  \
                    float v = accv[ntl][r];                                    \
                    v = fmaxf(v, __shfl_xor(v, 1));                            \
                    v = fmaxf(v, __shfl_xor(v, 8));                            \
                    v = fmaxf(v + bias4[r], 0.f);                              \
                    if (wrp) p2o[(g * 4 + r) * 16 + ntl * 4] = v;              \
                }                                                              \
            }                                                                  \
        }
        CONV2_EPI(accA, wv0);
        CONV2_EPI(accB, wv0 + 4);
#undef CONV2_EPI
    }
    __syncthreads();

    // ---- fc1: 256 -> 120, relu. 240 lanes; lane pair shares weight row,
    //      each lane does 4 instance-dots (ILP 4, fw1 read once per pair) ----
    if (tid < 240) {
        int o  = tid >> 1;                       // 0..119
        int pr = tid & 1;                        // instance group: 4*pr..4*pr+3
        const float4* wr = (const float4*)(fw1 + o * 256);
        const float4* q0 = (const float4*)(s_p2 + (4 * pr    ) * 256);
        const float4* q1 = (const float4*)(s_p2 + (4 * pr + 1) * 256);
        const float4* q2 = (const float4*)(s_p2 + (4 * pr + 2) * 256);
        const float4* q3 = (const float4*)(s_p2 + (4 * pr + 3) * 256);
        float a0 = 0.f, a1 = 0.f, a2 = 0.f, a3 = 0.f;
#pragma unroll 4
        for (int k = 0; k < 64; ++k) {
            float4 w4 = wr[k];
            float4 p;
            p = q0[k]; a0 = fmaf(w4.x,p.x,a0); a0 = fmaf(w4.y,p.y,a0); a0 = fmaf(w4.z,p.z,a0); a0 = fmaf(w4.w,p.w,a0);
            p = q1[k]; a1 = fmaf(w4.x,p.x,a1); a1 = fmaf(w4.y,p.y,a1); a1 = fmaf(w4.z,p.z,a1); a1 = fmaf(w4.w,p.w,a1);
            p = q2[k]; a2 = fmaf(w4.x,p.x,a2); a2 = fmaf(w4.y,p.y,a2); a2 = fmaf(w4.z,p.z,a2); a2 = fmaf(w4.w,p.w,a2);
            p = q3[k]; a3 = fmaf(w4.x,p.x,a3); a3 = fmaf(w4.y,p.y,a3); a3 = fmaf(w4.w,p.w,a3); a3 = fmaf(w4.z,p.z,a3);
        }
        float bb = fb1[o];
        s_f1[(4 * pr    ) * 120 + o] = fmaxf(a0 + bb, 0.f);
        s_f1[(4 * pr + 1) * 120 + o] = fmaxf(a1 + bb, 0.f);
        s_f1[(4 * pr + 2) * 120 + o] = fmaxf(a2 + bb, 0.f);
        s_f1[(4 * pr + 3) * 120 + o] = fmaxf(a3 + bb, 0.f);
    }
    __syncthreads();

    // ---- fc2: 120 -> 84, relu. 168 lanes, same pairing ----
    if (tid < 168) {
        int o  = tid >> 1;                       // 0..83
        int pr = tid & 1;
        const float4* wr = (const float4*)(fw2 + o * 120);
        const float4* q0 = (const float4*)(s_f1 + (4 * pr    ) * 120);
        const float4* q1 = (const float4*)(s_f1 + (4 * pr + 1) * 120);
        const float4* q2 = (const float4*)(s_f1 + (4 * pr + 2) * 120);
        const float4* q3 = (const float4*)(s_f1 + (4 * pr + 3) * 120);
        float a0 = 0.f, a1 = 0.f, a2 = 0.f, a3 = 0.f;
#pragma unroll 5
        for (int k = 0; k < 30; ++k) {
            float4 w4 = wr[k];
            float4 p;
            p = q0[k]; a0 = fmaf(w4.x,p.x,a0); a0 = fmaf(w4.y,p.y,a0); a0 = fmaf(w4.z,p.z,a0); a0 = fmaf(w4.w,p.w,a0);
            p = q1[k]; a1 = fmaf(w4.x,p.x,a1); a1 = fmaf(w4.y,p.y,a1); a1 = fmaf(w4.z,p.z,a1); a1 = fmaf(w4.w,p.w,a1);
            p = q2[k]; a2 = fmaf(w4.x,p.x,a2); a2 = fmaf(w4.y,p.y,a2); a2 = fmaf(w4.z,p.z,a2); a2 = fmaf(w4.w,p.w,a2);
            p = q3[k]; a3 = fmaf(w4.x,p.x,a3); a3 = fmaf(w4.y,p.y,a3); a3 = fmaf(w4.z,p.z,a3); a3 = fmaf(w4.w,p.w,a3);
        }
        float bb = fb2[o];
        s_f2[(4 * pr    ) * 84 + o] = fmaxf(a0 + bb, 0.f);
        s_f2[(4 * pr + 1) * 84 + o] = fmaxf(a1 + bb, 0.f);
        s_f2[(4 * pr + 2) * 84 + o] = fmaxf(a2 + bb, 0.f);
        s_f2[(4 * pr + 3) * 84 + o] = fmaxf(a3 + bb, 0.f);
    }
    __syncthreads();

    // ---- fc3: 84 -> 10. 80 lanes ----
    if (tid < 80) {
        int o    = tid % 10;
        int inst = tid / 10;                     // 0..7
        const float4* wr = (const float4*)(fw3 + o * 84);
        const float4* q0 = (const float4*)(s_f2 + inst * 84);
        float a0 = 0.f;
#pragma unroll
        for (int k = 0; k < 21; ++k) {
            float4 w4 = wr[k];
            float4 p = q0[k];
            a0 = fmaf(w4.x,p.x,a0); a0 = fmaf(w4.y,p.y,a0); a0 = fmaf(w4.z,p.z,a0); a0 = fmaf(w4.w,p.w,a0);
        }
        s_log[inst * 10 + o] = a0 + fb3[o];
    }
    __syncthreads();

    // ---- softmax (in-lane) + full convolution (len 19) + log ----
    if (tid < 19 * SPB) {
        int ls = tid / 19;                       // sample 0..3
        int t  = tid % 19;
        const float* la = &s_log[(ls * 2 + 0) * 10];
        const float* lb = &s_log[(ls * 2 + 1) * 10];
        float pa[10], pb[10];
        float mxa = la[0], mxb = lb[0];
#pragma unroll
        for (int j = 1; j < 10; ++j) { mxa = fmaxf(mxa, la[j]); mxb = fmaxf(mxb, lb[j]); }
        float sa = 0.f, sb = 0.f;
#pragma unroll
        for (int j = 0; j < 10; ++j) {
            pa[j] = __expf(la[j] - mxa); sa += pa[j];
            pb[j] = __expf(lb[j] - mxb); sb += pb[j];
        }
        float inv = 1.f / (sa * sb);
        int jlo = t - 9 > 0 ? t - 9 : 0;
        int jhi = t < 9 ? t : 9;
        float z = 0.f;
        for (int j = jlo; j <= jhi; ++j)
            z += pa[j] * pb[t - j];
        out[(size_t)(b0 + ls) * 19 + t] = __logf(z * inv);
    }
}

extern "C" void kernel_launch(void* const* d_in, const int* in_sizes, int n_in,
                              void* d_out, int out_size, void* d_ws, size_t ws_size,
                              hipStream_t stream) {
    const float* x   = (const float*)d_in[0];
    const float* cw1 = (const float*)d_in[1];
    const float* cb1 = (const float*)d_in[2];
    const float* cw2 = (const float*)d_in[3];
    const float* cb2 = (const float*)d_in[4];
    const float* fw1 = (const float*)d_in[5];
    const float* fb1 = (const float*)d_in[6];
    const float* fw2 = (const float*)d_in[7];
    const float* fb2 = (const float*)d_in[8];
    const float* fw3 = (const float*)d_in[9];
    const float* fb3 = (const float*)d_in[10];
    float* out = (float*)d_out;

    const int B = in_sizes[0] / (2 * 28 * 28);   // 16384

    lenet_fused<<<B / SPB, 256, 0, stream>>>(x, cw1, cb1, cw2, cb2,
                                             fw1, fb1, fw2, fb2, fw3, fb3, out);
}